// Round 2
// baseline (239.119 us; speedup 1.0000x reference)
//
#include <hip/hip_runtime.h>
#include <math.h>

// Problem constants
#define NTHREADS 256
#define TROWS 16            // rows (tokens) per block = one 16-row MFMA tile
#define TOKN 13824          // 24*24*24
#define MASKN 10368         // 0.75 * TOKN
#define UNMASKN 3456        // TOKN - MASKN
#define EMB 768
#define NPOS 24
#define NBATCH 4
#define ABLOCKS (TOKN / TROWS)    // 864 blocks (4 batches * 3456 unmask rows)
#define BBLOCKS (MASKN / TROWS)   // 648 blocks (mask rows, computed once, stored x4)
#define TABN (NPOS * 256)         // 6144 floats = 24 KB sincos table in d_ws
#define WN (64 * EMB)             // 49152 W elements

typedef __attribute__((ext_vector_type(8))) short short8;   // 8 bf16 = 4 VGPRs
typedef __attribute__((ext_vector_type(4))) float f32x4;

__device__ __forceinline__ short f2bf(float f) {
  union { float f; unsigned u; } c; c.f = f;
  unsigned u = c.u + 0x7FFFu + ((c.u >> 16) & 1u);   // RNE
  return (short)(u >> 16);
}

// Setup: sincos table + bf16-transposed W (wsW[col][k]) in d_ws + mask_idx out.
__global__ __launch_bounds__(NTHREADS) void setup_kernel(
    const float* __restrict__ W, const int* __restrict__ perm,
    float* __restrict__ tabg, short* __restrict__ wsW,
    float* __restrict__ out_idx)
{
  int i = blockIdx.x * NTHREADS + threadIdx.x;
  if (i < MASKN) out_idx[i] = (float)perm[i];
  if (i < TABN) {
    // inv_freq[j] = 10000^(-j/128) = 2^(-j * log2(10000)/128)
    const float c0 = 13.287712379549449f / 128.0f;
    int pos = i >> 8, e = i & 255, j = e >> 1;
    float s = (float)pos * exp2f(-(float)j * c0);
    tabg[i] = (e & 1) ? cosf(s) : sinf(s);
  }
  if (i < WN) {
    int col = i >> 6, k = i & 63;
    wsW[i] = f2bf(W[k * EMB + col]);   // wsW[col*64 + k]
  }
}

// Round-3 change: SWAPPED MFMA operands — compute (W^T patch^T) so the C/D
// fragment holds token = lane&15 and 4 CONSECUTIVE COLUMNS in the reg index.
// This turns the whole epilogue (pos-enc add, gamma/beta, stores) into
// float4 ops and shrinks the LN shuffle reduction from 32 to 4 shuffles.
// Round-4 fix: __builtin_nontemporal_store needs clang ext-vector (f32x4),
// not HIP_vector_type float4.
// NOTE: default launch_bounds only. Round-2 lesson: a min-waves clamp forced
// VGPR=64 and spilled the accumulators to scratch (2.2 GB of writes).
__global__ __launch_bounds__(NTHREADS) void fused_embed_ln_mfma(
    const float* __restrict__ x, const float* __restrict__ pb,
    const float* __restrict__ mt, const float* __restrict__ gmm,
    const float* __restrict__ bta, const int* __restrict__ perm,
    const float* __restrict__ tabg, const short* __restrict__ wsW,
    float* __restrict__ out)
{
  __shared__ __align__(16) short aLds[TROWS][72];  // bf16 A, +8 pad (2.3 KB)
  __shared__ int segbase[3][TROWS];                // h/w/d << 8 per row
  __shared__ float wred[TROWS][4][2];
  __shared__ float rowstat[TROWS][2];

  const int tid = threadIdx.x;
  const int blk = blockIdx.x;
  const bool isA = blk < ABLOCKS;

  // --- token indices + decomposed positions ---
  if (tid < TROWS) {
    int r;
    if (isA) {
      int u = (blk * TROWS) % UNMASKN + tid;  // 3456 % 16 == 0: one batch/block
      r = perm[MASKN + u];
    } else {
      r = perm[(blk - ABLOCKS) * TROWS + tid];
    }
    int h = r / 576; int rem = r - h * 576;
    int w = rem / 24; int d = rem - w * 24;
    segbase[0][tid] = h << 8; segbase[1][tid] = w << 8; segbase[2][tid] = d << 8;
  }
  __syncthreads();

  // --- stage 16 patch rows into LDS as bf16 ---
  {
    int t = tid >> 4, seg = tid & 15;
    float4 v;
    if (isA) {
      int b = (blk * TROWS) / UNMASKN;
      int h = segbase[0][t] >> 8, w = segbase[1][t] >> 8, d = segbase[2][t] >> 8;
      int ph = seg >> 2, pw = seg & 3;
      v = *(const float4*)(x +
          ((((long)b * 96 + h * 4 + ph) * 96 + (w * 4 + pw)) * 96 + d * 4));
    } else {
      int m0 = (blk - ABLOCKS) * TROWS;
      v = *(const float4*)(mt + (long)(m0 + t) * 64 + seg * 4);
    }
    short4 s4; s4.x = f2bf(v.x); s4.y = f2bf(v.y); s4.z = f2bf(v.z); s4.w = f2bf(v.w);
    *(short4*)&aLds[t][seg * 4] = s4;
  }
  __syncthreads();

  // --- MFMA GEMM: wave wv covers cols [wv*192, wv*192+192) = 12 tiles ---
  const int wv = tid >> 6, lane = tid & 63;
  const int n16 = lane & 15, q = lane >> 4;
  const int q4 = q * 4;
  const int colbase = wv * 192;

  // Patch frag (used as operand B after swap): B[k=q*8+j][col=n16]
  short8 af0 = *(const short8*)&aLds[n16][q * 8];
  short8 af1 = *(const short8*)&aLds[n16][32 + q * 8];

  f32x4 acc[12];
  const short* wp = wsW + (colbase + n16) * 64 + q * 8;
  #pragma unroll
  for (int jt = 0; jt < 12; ++jt) {
    // W frag (operand A after swap): A[row=n16 -> col colbase+jt*16+n16][k=q*8+j]
    short8 bf0 = *(const short8*)(wp + jt * 16 * 64);
    short8 bf1 = *(const short8*)(wp + jt * 16 * 64 + 32);
    f32x4 c = {0.f, 0.f, 0.f, 0.f};
    c = __builtin_amdgcn_mfma_f32_16x16x32_bf16(bf0, af0, c, 0, 0, 0);
    c = __builtin_amdgcn_mfma_f32_16x16x32_bf16(bf1, af1, c, 0, 0, 0);
    acc[jt] = c;   // acc[jt][r] = out[token=n16][col = colbase + jt*16 + q4 + r]
  }

  // --- add bias + pos-enc (float4), per-token LN partials ---
  // A 16-aligned 16-wide tile never crosses a 256-col segment boundary, and a
  // 4-aligned 4-wide reg group never does either -> seg uniform per (wv,jt).
  const float* t0 = tabg + segbase[0][n16];
  const float* t1 = tabg + segbase[1][n16];
  const float* t2 = tabg + segbase[2][n16];

  float s = 0.f, qq = 0.f;
  #pragma unroll
  for (int jt = 0; jt < 12; ++jt) {
    int colb = colbase + jt * 16 + q4;
    int seg = colb >> 8;
    int cb = colb & 255;
    const float* tp = (seg == 0) ? t0 : ((seg == 1) ? t1 : t2);
    f32x4 pbv = *(const f32x4*)(pb + colb);
    f32x4 tv  = *(const f32x4*)(tp + cb);
    float v0 = acc[jt][0] + pbv[0] + tv[0];
    float v1 = acc[jt][1] + pbv[1] + tv[1];
    float v2 = acc[jt][2] + pbv[2] + tv[2];
    float v3 = acc[jt][3] + pbv[3] + tv[3];
    acc[jt][0] = v0; acc[jt][1] = v1; acc[jt][2] = v2; acc[jt][3] = v3;
    s  += (v0 + v1) + (v2 + v3);
    qq += (v0 * v0 + v1 * v1) + (v2 * v2 + v3 * v3);
  }
  // token row lives in n16; reduce across q (lane bits 4,5) only
  s  += __shfl_xor(s,  16, 64);
  s  += __shfl_xor(s,  32, 64);
  qq += __shfl_xor(qq, 16, 64);
  qq += __shfl_xor(qq, 32, 64);
  if (lane < 16) { wred[lane][wv][0] = s; wred[lane][wv][1] = qq; }
  __syncthreads();
  if (tid < TROWS) {
    float ss = wred[tid][0][0] + wred[tid][1][0] + wred[tid][2][0] + wred[tid][3][0];
    float qs = wred[tid][0][1] + wred[tid][1][1] + wred[tid][2][1] + wred[tid][3][1];
    float mean = ss * (1.0f / 768.0f);
    float var = qs * (1.0f / 768.0f) - mean * mean;   // biased, matches jnp.var
    rowstat[tid][0] = mean;
    rowstat[tid][1] = 1.0f / sqrtf(var + 0.001f);     // LN_EPS
  }
  __syncthreads();

  const float mr = rowstat[n16][0];
  const float rr = rowstat[n16][1];

  // --- normalize + f32x4 nontemporal stores (mask rows broadcast x4) ---
  if (isA) {
    int row0 = blk * TROWS;
    int b = row0 / UNMASKN;
    int u0 = row0 % UNMASKN;
    float* base = out + ((long)b * TOKN + u0 + n16) * EMB + colbase + q4;
    #pragma unroll
    for (int jt = 0; jt < 12; ++jt) {
      int colb = colbase + jt * 16 + q4;
      f32x4 g  = *(const f32x4*)(gmm + colb);
      f32x4 bb = *(const f32x4*)(bta + colb);
      f32x4 o;
      o[0] = (acc[jt][0] - mr) * rr * g[0] + bb[0];
      o[1] = (acc[jt][1] - mr) * rr * g[1] + bb[1];
      o[2] = (acc[jt][2] - mr) * rr * g[2] + bb[2];
      o[3] = (acc[jt][3] - mr) * rr * g[3] + bb[3];
      __builtin_nontemporal_store(o, (f32x4*)(base + jt * 16));
    }
  } else {
    int m0 = (blk - ABLOCKS) * TROWS;
    float* base = out + ((long)UNMASKN + m0 + n16) * EMB + colbase + q4;
    #pragma unroll
    for (int jt = 0; jt < 12; ++jt) {
      int colb = colbase + jt * 16 + q4;
      f32x4 g  = *(const f32x4*)(gmm + colb);
      f32x4 bb = *(const f32x4*)(bta + colb);
      f32x4 o;
      o[0] = (acc[jt][0] - mr) * rr * g[0] + bb[0];
      o[1] = (acc[jt][1] - mr) * rr * g[1] + bb[1];
      o[2] = (acc[jt][2] - mr) * rr * g[2] + bb[2];
      o[3] = (acc[jt][3] - mr) * rr * g[3] + bb[3];
      float* p = base + jt * 16;
      #pragma unroll
      for (int b4 = 0; b4 < NBATCH; ++b4) {
        __builtin_nontemporal_store(o, (f32x4*)p);
        p += (long)TOKN * EMB;
      }
    }
  }
}

extern "C" void kernel_launch(void* const* d_in, const int* in_sizes, int n_in,
                              void* d_out, int out_size, void* d_ws, size_t ws_size,
                              hipStream_t stream) {
  const float* x    = (const float*)d_in[0];
  const float* W    = (const float*)d_in[1];
  const float* pb   = (const float*)d_in[2];
  const float* mt   = (const float*)d_in[3];
  const float* gmm  = (const float*)d_in[4];
  const float* bta  = (const float*)d_in[5];
  const int*   perm = (const int*)d_in[6];
  float* out = (float*)d_out;
  float* out_idx = out + (long)NBATCH * TOKN * EMB;   // 42,467,328

  float* tabg = (float*)d_ws;                         // 24 KB sincos table
  short* wsW  = (short*)((char*)d_ws + TABN * 4);     // 96 KB bf16 W^T [col][k]

  setup_kernel<<<(WN + NTHREADS - 1) / NTHREADS, NTHREADS, 0, stream>>>(
      W, perm, tabg, wsW, out_idx);
  fused_embed_ln_mfma<<<ABLOCKS + BBLOCKS, NTHREADS, 0, stream>>>(
      x, pb, mt, gmm, bta, perm, tabg, wsW, out);
}

// Round 3
// 223.126 us; speedup vs baseline: 1.0717x; 1.0717x over previous
//
#include <hip/hip_runtime.h>
#include <math.h>

// Problem constants
#define NTHREADS 256
#define TROWS 16            // rows (tokens) per block = one 16-row MFMA tile
#define TOKN 13824          // 24*24*24
#define MASKN 10368         // 0.75 * TOKN
#define UNMASKN 3456        // TOKN - MASKN
#define EMB 768
#define NPOS 24
#define NBATCH 4
#define ABLOCKS (TOKN / TROWS)    // 864 blocks (4 batches * 3456 unmask rows)
#define BBLOCKS (MASKN / TROWS)   // 648 blocks (mask rows, computed once, stored x4)
#define TABN (NPOS * 256)         // 6144 floats = 24 KB sincos table in d_ws
#define WN (64 * EMB)             // 49152 W elements

typedef __attribute__((ext_vector_type(8))) short short8;   // 8 bf16 = 4 VGPRs
typedef __attribute__((ext_vector_type(4))) float f32x4;

__device__ __forceinline__ short f2bf(float f) {
  union { float f; unsigned u; } c; c.f = f;
  unsigned u = c.u + 0x7FFFu + ((c.u >> 16) & 1u);   // RNE
  return (short)(u >> 16);
}

// Setup: sincos table + bf16-transposed W (wsW[col][k]) in d_ws + mask_idx out.
__global__ __launch_bounds__(NTHREADS) void setup_kernel(
    const float* __restrict__ W, const int* __restrict__ perm,
    float* __restrict__ tabg, short* __restrict__ wsW,
    float* __restrict__ out_idx)
{
  int i = blockIdx.x * NTHREADS + threadIdx.x;
  if (i < MASKN) out_idx[i] = (float)perm[i];
  if (i < TABN) {
    // inv_freq[j] = 10000^(-j/128) = 2^(-j * log2(10000)/128)
    const float c0 = 13.287712379549449f / 128.0f;
    int pos = i >> 8, e = i & 255, j = e >> 1;
    float s = (float)pos * exp2f(-(float)j * c0);
    tabg[i] = (e & 1) ? cosf(s) : sinf(s);
  }
  if (i < WN) {
    int col = i >> 6, k = i & 63;
    wsW[i] = f2bf(W[k * EMB + col]);   // wsW[col*64 + k]
  }
}

// Round-3: SWAPPED MFMA operands — C/D holds token = lane&15, 4 consecutive
// cols in the reg index -> float4 epilogue, 4-shuffle LN reduction.
// Round-5: REVERT nontemporal stores (round-4). nt defeated L2 write-combining
// of the 64B per-row segments -> partial-line HBM writes, fused ~102->~122us.
// Plain f32x4 stores let L2 write-back merge segments into full lines.
// NOTE: default launch_bounds only. Round-2 lesson: a min-waves clamp forced
// VGPR=64 and spilled the accumulators to scratch (2.2 GB of writes).
__global__ __launch_bounds__(NTHREADS) void fused_embed_ln_mfma(
    const float* __restrict__ x, const float* __restrict__ pb,
    const float* __restrict__ mt, const float* __restrict__ gmm,
    const float* __restrict__ bta, const int* __restrict__ perm,
    const float* __restrict__ tabg, const short* __restrict__ wsW,
    float* __restrict__ out)
{
  __shared__ __align__(16) short aLds[TROWS][72];  // bf16 A, +8 pad (2.3 KB)
  __shared__ int segbase[3][TROWS];                // h/w/d << 8 per row
  __shared__ float wred[TROWS][4][2];
  __shared__ float rowstat[TROWS][2];

  const int tid = threadIdx.x;
  const int blk = blockIdx.x;
  const bool isA = blk < ABLOCKS;

  // --- token indices + decomposed positions ---
  if (tid < TROWS) {
    int r;
    if (isA) {
      int u = (blk * TROWS) % UNMASKN + tid;  // 3456 % 16 == 0: one batch/block
      r = perm[MASKN + u];
    } else {
      r = perm[(blk - ABLOCKS) * TROWS + tid];
    }
    int h = r / 576; int rem = r - h * 576;
    int w = rem / 24; int d = rem - w * 24;
    segbase[0][tid] = h << 8; segbase[1][tid] = w << 8; segbase[2][tid] = d << 8;
  }
  __syncthreads();

  // --- stage 16 patch rows into LDS as bf16 ---
  {
    int t = tid >> 4, seg = tid & 15;
    float4 v;
    if (isA) {
      int b = (blk * TROWS) / UNMASKN;
      int h = segbase[0][t] >> 8, w = segbase[1][t] >> 8, d = segbase[2][t] >> 8;
      int ph = seg >> 2, pw = seg & 3;
      v = *(const float4*)(x +
          ((((long)b * 96 + h * 4 + ph) * 96 + (w * 4 + pw)) * 96 + d * 4));
    } else {
      int m0 = (blk - ABLOCKS) * TROWS;
      v = *(const float4*)(mt + (long)(m0 + t) * 64 + seg * 4);
    }
    short4 s4; s4.x = f2bf(v.x); s4.y = f2bf(v.y); s4.z = f2bf(v.z); s4.w = f2bf(v.w);
    *(short4*)&aLds[t][seg * 4] = s4;
  }
  __syncthreads();

  // --- MFMA GEMM: wave wv covers cols [wv*192, wv*192+192) = 12 tiles ---
  const int wv = tid >> 6, lane = tid & 63;
  const int n16 = lane & 15, q = lane >> 4;
  const int q4 = q * 4;
  const int colbase = wv * 192;

  // Patch frag (used as operand B after swap): B[k=q*8+j][col=n16]
  short8 af0 = *(const short8*)&aLds[n16][q * 8];
  short8 af1 = *(const short8*)&aLds[n16][32 + q * 8];

  f32x4 acc[12];
  const short* wp = wsW + (colbase + n16) * 64 + q * 8;
  #pragma unroll
  for (int jt = 0; jt < 12; ++jt) {
    // W frag (operand A after swap): A[row=n16 -> col colbase+jt*16+n16][k=q*8+j]
    short8 bf0 = *(const short8*)(wp + jt * 16 * 64);
    short8 bf1 = *(const short8*)(wp + jt * 16 * 64 + 32);
    f32x4 c = {0.f, 0.f, 0.f, 0.f};
    c = __builtin_amdgcn_mfma_f32_16x16x32_bf16(bf0, af0, c, 0, 0, 0);
    c = __builtin_amdgcn_mfma_f32_16x16x32_bf16(bf1, af1, c, 0, 0, 0);
    acc[jt] = c;   // acc[jt][r] = out[token=n16][col = colbase + jt*16 + q4 + r]
  }

  // --- add bias + pos-enc (float4), per-token LN partials ---
  // A 16-aligned 16-wide tile never crosses a 256-col segment boundary, and a
  // 4-aligned 4-wide reg group never does either -> seg uniform per (wv,jt).
  const float* t0 = tabg + segbase[0][n16];
  const float* t1 = tabg + segbase[1][n16];
  const float* t2 = tabg + segbase[2][n16];

  float s = 0.f, qq = 0.f;
  #pragma unroll
  for (int jt = 0; jt < 12; ++jt) {
    int colb = colbase + jt * 16 + q4;
    int seg = colb >> 8;
    int cb = colb & 255;
    const float* tp = (seg == 0) ? t0 : ((seg == 1) ? t1 : t2);
    f32x4 pbv = *(const f32x4*)(pb + colb);
    f32x4 tv  = *(const f32x4*)(tp + cb);
    float v0 = acc[jt][0] + pbv[0] + tv[0];
    float v1 = acc[jt][1] + pbv[1] + tv[1];
    float v2 = acc[jt][2] + pbv[2] + tv[2];
    float v3 = acc[jt][3] + pbv[3] + tv[3];
    acc[jt][0] = v0; acc[jt][1] = v1; acc[jt][2] = v2; acc[jt][3] = v3;
    s  += (v0 + v1) + (v2 + v3);
    qq += (v0 * v0 + v1 * v1) + (v2 * v2 + v3 * v3);
  }
  // token row lives in n16; reduce across q (lane bits 4,5) only
  s  += __shfl_xor(s,  16, 64);
  s  += __shfl_xor(s,  32, 64);
  qq += __shfl_xor(qq, 16, 64);
  qq += __shfl_xor(qq, 32, 64);
  if (lane < 16) { wred[lane][wv][0] = s; wred[lane][wv][1] = qq; }
  __syncthreads();
  if (tid < TROWS) {
    float ss = wred[tid][0][0] + wred[tid][1][0] + wred[tid][2][0] + wred[tid][3][0];
    float qs = wred[tid][0][1] + wred[tid][1][1] + wred[tid][2][1] + wred[tid][3][1];
    float mean = ss * (1.0f / 768.0f);
    float var = qs * (1.0f / 768.0f) - mean * mean;   // biased, matches jnp.var
    rowstat[tid][0] = mean;
    rowstat[tid][1] = 1.0f / sqrtf(var + 0.001f);     // LN_EPS
  }
  __syncthreads();

  const float mr = rowstat[n16][0];
  const float rr = rowstat[n16][1];

  // --- normalize + f32x4 stores (mask rows broadcast x4) ---
  if (isA) {
    int row0 = blk * TROWS;
    int b = row0 / UNMASKN;
    int u0 = row0 % UNMASKN;
    float* base = out + ((long)b * TOKN + u0 + n16) * EMB + colbase + q4;
    #pragma unroll
    for (int jt = 0; jt < 12; ++jt) {
      int colb = colbase + jt * 16 + q4;
      f32x4 g  = *(const f32x4*)(gmm + colb);
      f32x4 bb = *(const f32x4*)(bta + colb);
      f32x4 o;
      o[0] = (acc[jt][0] - mr) * rr * g[0] + bb[0];
      o[1] = (acc[jt][1] - mr) * rr * g[1] + bb[1];
      o[2] = (acc[jt][2] - mr) * rr * g[2] + bb[2];
      o[3] = (acc[jt][3] - mr) * rr * g[3] + bb[3];
      *(f32x4*)(base + jt * 16) = o;
    }
  } else {
    int m0 = (blk - ABLOCKS) * TROWS;
    float* base = out + ((long)UNMASKN + m0 + n16) * EMB + colbase + q4;
    #pragma unroll
    for (int jt = 0; jt < 12; ++jt) {
      int colb = colbase + jt * 16 + q4;
      f32x4 g  = *(const f32x4*)(gmm + colb);
      f32x4 bb = *(const f32x4*)(bta + colb);
      f32x4 o;
      o[0] = (acc[jt][0] - mr) * rr * g[0] + bb[0];
      o[1] = (acc[jt][1] - mr) * rr * g[1] + bb[1];
      o[2] = (acc[jt][2] - mr) * rr * g[2] + bb[2];
      o[3] = (acc[jt][3] - mr) * rr * g[3] + bb[3];
      float* p = base + jt * 16;
      #pragma unroll
      for (int b4 = 0; b4 < NBATCH; ++b4) {
        *(f32x4*)p = o;
        p += (long)TOKN * EMB;
      }
    }
  }
}

extern "C" void kernel_launch(void* const* d_in, const int* in_sizes, int n_in,
                              void* d_out, int out_size, void* d_ws, size_t ws_size,
                              hipStream_t stream) {
  const float* x    = (const float*)d_in[0];
  const float* W    = (const float*)d_in[1];
  const float* pb   = (const float*)d_in[2];
  const float* mt   = (const float*)d_in[3];
  const float* gmm  = (const float*)d_in[4];
  const float* bta  = (const float*)d_in[5];
  const int*   perm = (const int*)d_in[6];
  float* out = (float*)d_out;
  float* out_idx = out + (long)NBATCH * TOKN * EMB;   // 42,467,328

  float* tabg = (float*)d_ws;                         // 24 KB sincos table
  short* wsW  = (short*)((char*)d_ws + TABN * 4);     // 96 KB bf16 W^T [col][k]

  setup_kernel<<<(WN + NTHREADS - 1) / NTHREADS, NTHREADS, 0, stream>>>(
      W, perm, tabg, wsW, out_idx);
  fused_embed_ln_mfma<<<ABLOCKS + BBLOCKS, NTHREADS, 0, stream>>>(
      x, pb, mt, gmm, bta, perm, tabg, wsW, out);
}

// Round 4
// 220.705 us; speedup vs baseline: 1.0834x; 1.0110x over previous
//
#include <hip/hip_runtime.h>
#include <math.h>

// Problem constants
#define NTHREADS 256
#define TROWS 16            // rows (tokens) per block = one 16-row MFMA tile
#define TOKN 13824          // 24*24*24
#define MASKN 10368         // 0.75 * TOKN
#define UNMASKN 3456        // TOKN - MASKN
#define EMB 768
#define NPOS 24
#define NBATCH 4
#define ABLOCKS (TOKN / TROWS)    // 864 blocks (4 batches * 3456 unmask rows)
#define BBLOCKS (MASKN / TROWS)   // 648 blocks (mask rows, computed once, stored x4)
#define TABN (NPOS * 256)         // 6144 floats = 24 KB sincos table in d_ws
#define WN (64 * EMB)             // 49152 W elements

typedef __attribute__((ext_vector_type(8))) short short8;   // 8 bf16 = 4 VGPRs
typedef __attribute__((ext_vector_type(4))) float f32x4;

__device__ __forceinline__ short f2bf(float f) {
  union { float f; unsigned u; } c; c.f = f;
  unsigned u = c.u + 0x7FFFu + ((c.u >> 16) & 1u);   // RNE
  return (short)(u >> 16);
}

// Setup: sincos table + bf16-transposed W (wsW[col][k]) in d_ws + mask_idx out.
__global__ __launch_bounds__(NTHREADS) void setup_kernel(
    const float* __restrict__ W, const int* __restrict__ perm,
    float* __restrict__ tabg, short* __restrict__ wsW,
    float* __restrict__ out_idx)
{
  int i = blockIdx.x * NTHREADS + threadIdx.x;
  if (i < MASKN) out_idx[i] = (float)perm[i];
  if (i < TABN) {
    // inv_freq[j] = 10000^(-j/128) = 2^(-j * log2(10000)/128)
    const float c0 = 13.287712379549449f / 128.0f;
    int pos = i >> 8, e = i & 255, j = e >> 1;
    float s = (float)pos * exp2f(-(float)j * c0);
    tabg[i] = (e & 1) ? cosf(s) : sinf(s);
  }
  if (i < WN) {
    int col = i >> 6, k = i & 63;
    wsW[i] = f2bf(W[k * EMB + col]);   // wsW[col*64 + k]
  }
}

// Round-3: SWAPPED MFMA operands — C/D holds token = lane&15, 4 consecutive
// cols in the reg index -> float4 epilogue, 4-shuffle LN reduction.
// Round-5: plain f32x4 stores (nt defeated L2 write-combining, +10us).
// Round-6: THEORY = R3's vector epilogue pushed VGPR past the 128 occupancy
// boundary (waves/SIMD halve at 64/128/256) -> 2 blocks/CU instead of 4.
//  - __launch_bounds__(256,4): cap VGPR at 128 (4 waves/EU). NOT the round-2
//    disaster (that clamp forced 64 and spilled).
//  - syncs 4 -> 2: segbase folded into staging (redundant per-lane compute);
//    LN stats computed by all lanes from 4 LDS partials (no tid<16 phase).
//  - store epilogue as single FMA per element (scale/off precomputed).
__global__ __launch_bounds__(NTHREADS, 4) void fused_embed_ln_mfma(
    const float* __restrict__ x, const float* __restrict__ pb,
    const float* __restrict__ mt, const float* __restrict__ gmm,
    const float* __restrict__ bta, const int* __restrict__ perm,
    const float* __restrict__ tabg, const short* __restrict__ wsW,
    float* __restrict__ out)
{
  __shared__ __align__(16) short aLds[TROWS][72];  // bf16 A, +8 pad (2.3 KB)
  __shared__ int segbase[3][TROWS];                // h/w/d << 8 per row
  __shared__ float wred[TROWS][4][2];

  const int tid = threadIdx.x;
  const int blk = blockIdx.x;
  const bool isA = blk < ABLOCKS;

  // --- stage 16 patch rows into LDS as bf16; every lane redundantly computes
  // its row's token index + (h,w,d) so only ONE barrier is needed ---
  {
    int t = tid >> 4, seg = tid & 15;
    int r;
    if (isA) {
      r = perm[MASKN + (blk * TROWS) % UNMASKN + t];  // 3456%16==0: 1 batch/blk
    } else {
      r = perm[(blk - ABLOCKS) * TROWS + t];
    }
    int h = r / 576; int rem = r - h * 576;
    int w = rem / 24; int d = rem - w * 24;
    if (seg < 3) segbase[seg][t] = (seg == 0 ? h : (seg == 1 ? w : d)) << 8;

    float4 v;
    if (isA) {
      int b = (blk * TROWS) / UNMASKN;
      int ph = seg >> 2, pw = seg & 3;
      v = *(const float4*)(x +
          ((((long)b * 96 + h * 4 + ph) * 96 + (w * 4 + pw)) * 96 + d * 4));
    } else {
      int m0 = (blk - ABLOCKS) * TROWS;
      v = *(const float4*)(mt + (long)(m0 + t) * 64 + seg * 4);
    }
    short4 s4; s4.x = f2bf(v.x); s4.y = f2bf(v.y); s4.z = f2bf(v.z); s4.w = f2bf(v.w);
    *(short4*)&aLds[t][seg * 4] = s4;
  }
  __syncthreads();                                   // barrier #1

  // --- MFMA GEMM: wave wv covers cols [wv*192, wv*192+192) = 12 tiles ---
  const int wv = tid >> 6, lane = tid & 63;
  const int n16 = lane & 15, q = lane >> 4;
  const int q4 = q * 4;
  const int colbase = wv * 192;

  // Patch frag (operand B after swap): B[k=q*8+j][col=n16]
  short8 af0 = *(const short8*)&aLds[n16][q * 8];
  short8 af1 = *(const short8*)&aLds[n16][32 + q * 8];

  f32x4 acc[12];
  const short* wp = wsW + (colbase + n16) * 64 + q * 8;
  #pragma unroll
  for (int jt = 0; jt < 12; ++jt) {
    // W frag (operand A after swap): A[row -> col colbase+jt*16+n16][k=q*8+j]
    short8 bf0 = *(const short8*)(wp + jt * 16 * 64);
    short8 bf1 = *(const short8*)(wp + jt * 16 * 64 + 32);
    f32x4 c = {0.f, 0.f, 0.f, 0.f};
    c = __builtin_amdgcn_mfma_f32_16x16x32_bf16(bf0, af0, c, 0, 0, 0);
    c = __builtin_amdgcn_mfma_f32_16x16x32_bf16(bf1, af1, c, 0, 0, 0);
    acc[jt] = c;   // acc[jt][r] = out[token=n16][col = colbase + jt*16 + q4 + r]
  }

  // --- add bias + pos-enc (float4), per-token LN partials ---
  // 16-aligned tiles / 4-aligned reg groups never cross a 256-col segment.
  const float* t0 = tabg + segbase[0][n16];
  const float* t1 = tabg + segbase[1][n16];
  const float* t2 = tabg + segbase[2][n16];

  float s = 0.f, qq = 0.f;
  #pragma unroll
  for (int jt = 0; jt < 12; ++jt) {
    int colb = colbase + jt * 16 + q4;
    int seg = colb >> 8;
    int cb = colb & 255;
    const float* tp = (seg == 0) ? t0 : ((seg == 1) ? t1 : t2);
    f32x4 pbv = *(const f32x4*)(pb + colb);
    f32x4 tv  = *(const f32x4*)(tp + cb);
    float v0 = acc[jt][0] + pbv[0] + tv[0];
    float v1 = acc[jt][1] + pbv[1] + tv[1];
    float v2 = acc[jt][2] + pbv[2] + tv[2];
    float v3 = acc[jt][3] + pbv[3] + tv[3];
    acc[jt][0] = v0; acc[jt][1] = v1; acc[jt][2] = v2; acc[jt][3] = v3;
    s  += (v0 + v1) + (v2 + v3);
    qq += (v0 * v0 + v1 * v1) + (v2 * v2 + v3 * v3);
  }
  // token row lives in n16; reduce across q (lane bits 4,5) only
  s  += __shfl_xor(s,  16, 64);
  s  += __shfl_xor(s,  32, 64);
  qq += __shfl_xor(qq, 16, 64);
  qq += __shfl_xor(qq, 32, 64);
  if (lane < 16) { wred[lane][wv][0] = s; wred[lane][wv][1] = qq; }
  __syncthreads();                                   // barrier #2 (last)

  // every lane computes its row's stats from the 4 wave partials
  float ss = wred[n16][0][0] + wred[n16][1][0] + wred[n16][2][0] + wred[n16][3][0];
  float qs = wred[n16][0][1] + wred[n16][1][1] + wred[n16][2][1] + wred[n16][3][1];
  float mean = ss * (1.0f / 768.0f);
  float var = qs * (1.0f / 768.0f) - mean * mean;    // biased, matches jnp.var
  float rstd = 1.0f / sqrtf(var + 0.001f);           // LN_EPS

  // --- normalize + f32x4 stores (mask rows broadcast x4) ---
  if (isA) {
    int row0 = blk * TROWS;
    int b = row0 / UNMASKN;
    int u0 = row0 % UNMASKN;
    float* base = out + ((long)b * TOKN + u0 + n16) * EMB + colbase + q4;
    #pragma unroll
    for (int jt = 0; jt < 12; ++jt) {
      int colb = colbase + jt * 16 + q4;
      f32x4 g  = *(const f32x4*)(gmm + colb);
      f32x4 bb = *(const f32x4*)(bta + colb);
      f32x4 o;
      #pragma unroll
      for (int r = 0; r < 4; ++r) {
        float sc = rstd * g[r];
        o[r] = acc[jt][r] * sc + (bb[r] - mean * sc);
      }
      *(f32x4*)(base + jt * 16) = o;
    }
  } else {
    int m0 = (blk - ABLOCKS) * TROWS;
    float* base = out + ((long)UNMASKN + m0 + n16) * EMB + colbase + q4;
    #pragma unroll
    for (int jt = 0; jt < 12; ++jt) {
      int colb = colbase + jt * 16 + q4;
      f32x4 g  = *(const f32x4*)(gmm + colb);
      f32x4 bb = *(const f32x4*)(bta + colb);
      f32x4 o;
      #pragma unroll
      for (int r = 0; r < 4; ++r) {
        float sc = rstd * g[r];
        o[r] = acc[jt][r] * sc + (bb[r] - mean * sc);
      }
      float* p = base + jt * 16;
      #pragma unroll
      for (int b4 = 0; b4 < NBATCH; ++b4) {
        *(f32x4*)p = o;
        p += (long)TOKN * EMB;
      }
    }
  }
}

extern "C" void kernel_launch(void* const* d_in, const int* in_sizes, int n_in,
                              void* d_out, int out_size, void* d_ws, size_t ws_size,
                              hipStream_t stream) {
  const float* x    = (const float*)d_in[0];
  const float* W    = (const float*)d_in[1];
  const float* pb   = (const float*)d_in[2];
  const float* mt   = (const float*)d_in[3];
  const float* gmm  = (const float*)d_in[4];
  const float* bta  = (const float*)d_in[5];
  const int*   perm = (const int*)d_in[6];
  float* out = (float*)d_out;
  float* out_idx = out + (long)NBATCH * TOKN * EMB;   // 42,467,328

  float* tabg = (float*)d_ws;                         // 24 KB sincos table
  short* wsW  = (short*)((char*)d_ws + TABN * 4);     // 96 KB bf16 W^T [col][k]

  setup_kernel<<<(WN + NTHREADS - 1) / NTHREADS, NTHREADS, 0, stream>>>(
      W, perm, tabg, wsW, out_idx);
  fused_embed_ln_mfma<<<ABLOCKS + BBLOCKS, NTHREADS, 0, stream>>>(
      x, pb, mt, gmm, bta, perm, tabg, wsW, out);
}